// Round 3
// baseline (219.076 us; speedup 1.0000x reference)
//
#include <hip/hip_runtime.h>
#include <hip/hip_bf16.h>

#define TT 200
#define EE 64
#define H1S 104   // u16 stride of per-wave h1 scratch (208 B rows: 16B-aligned, 2-way banks = free)

typedef unsigned short u16;
typedef unsigned int u32;
typedef __attribute__((ext_vector_type(8))) short bfrag;   // 8 bf16 in 4 VGPRs
typedef __attribute__((ext_vector_type(4))) float f32x4;

__device__ __forceinline__ u16 f2bf(float f) {
    __hip_bfloat16 h(f);                       // RNE, HW cvt op on gfx950
    return __builtin_bit_cast(u16, h);
}
__device__ __forceinline__ float sigmoid_fast(float x) {
    return __builtin_amdgcn_rcpf(1.0f + __expf(-x));
}

// Pre-pack W1k (rows 64..127 of W1) and W2 into MFMA B-fragment order.
// Slot bijection (must match A-frag construction in main kernel):
//   k = ks*32 + (lane>>4)*8 + j ,  n = nt*16 + (lane&15)
__global__ void prep_frags(const float* __restrict__ W1, const float* __restrict__ W2,
                           u16* __restrict__ B1f, u16* __restrict__ B2f) {
    int idx = blockIdx.x * 256 + threadIdx.x;
    if (idx < 5 * 2 * 64 * 8) {  // GEMM1: K=64 (2 ks), N=80 (5 nt)
        int j = idx & 7, l = (idx >> 3) & 63, ks = (idx >> 9) & 1, nt = idx >> 10;
        int k = ks * 32 + ((l >> 4) << 3) + j;
        int n = nt * 16 + (l & 15);
        B1f[idx] = f2bf(W1[(64 + k) * 80 + n]);
    }
    if (idx < 3 * 3 * 64 * 8) {  // GEMM2: K=96 pad (3 ks), N=48 pad (3 nt)
        int j = idx & 7, l = (idx >> 3) & 63, ks = (idx >> 9) % 3, nt = idx / 1536;
        int k = ks * 32 + ((l >> 4) << 3) + j;
        int n = nt * 16 + (l & 15);
        B2f[idx] = (k < 80 && n < 40) ? f2bf(W2[k * 40 + n]) : (u16)0;
    }
}

__global__ __launch_bounds__(256, 4) void din_mfma(
    const float* __restrict__ queries,     // (B,1,64)
    const float* __restrict__ keys,        // (B,200,64)
    const int*   __restrict__ keys_length, // (B,1)
    const float* __restrict__ W1,          // (128,80)
    const float* __restrict__ b1,          // (80)
    const float* __restrict__ b2,          // (40)
    const float* __restrict__ wk,          // (40)
    const float* __restrict__ bias,        // (1)
    const u16*   __restrict__ B1f,
    const u16*   __restrict__ B2f,
    float* __restrict__ out)               // (B,1,64)
{
    __shared__ __align__(16) u16 b1ls[5 * 2 * 64 * 8];   // 10240 B
    __shared__ __align__(16) u16 b2ls[3 * 3 * 64 * 8];   // 9216 B
    __shared__ __align__(16) u16 h1w[4][16][H1S];        // per-wave h1 scratch, 13312 B
    __shared__ float qb1s[80];
    __shared__ float sw[208];
    __shared__ float sred[2];
    __shared__ float partial[4][EE];

    const int b    = blockIdx.x;
    const int tid  = threadIdx.x;
    const int lane = tid & 63;
    const int wv   = tid >> 6;
    const int l15  = lane & 15;
    const int lhi  = lane >> 4;

    const float* kb = keys + (size_t)b * (TT * EE);
    const float* q  = queries + (size_t)b * EE;
    const int len   = keys_length[b];
    const float biass = bias[0];
    const float NEG = -4294967296.0f;

    // --- copy B fragments to LDS (16B chunks, coalesced) ---
    for (int c = tid; c < 640; c += 256)
        *reinterpret_cast<float4*>(&b1ls[c * 8]) = reinterpret_cast<const float4*>(B1f)[c];
    for (int c = tid; c < 576; c += 256)
        *reinterpret_cast<float4*>(&b2ls[c * 8]) = reinterpret_cast<const float4*>(B2f)[c];

    // --- zero h1 pad cols 80..95 of this wave's scratch (read as k=80..95 zeros) ---
    *reinterpret_cast<unsigned long long*>(&h1w[wv][lane >> 2][80 + (lane & 3) * 4]) = 0ULL;

    // --- qb1 = q @ W1[0:64] + b1 (wave-uniform q/W1 -> scalar loads) ---
    if (tid < 80) {
        float acc = b1[tid];
        #pragma unroll
        for (int i = 0; i < EE; ++i)
            acc = fmaf(q[i], W1[i * 80 + tid], acc);
        qb1s[tid] = acc;
    }
    __syncthreads();   // barrier 1 of 2 (qb1s + B-frag LDS ready)

    float qinit[5];
    #pragma unroll
    for (int nt = 0; nt < 5; ++nt) qinit[nt] = qb1s[nt * 16 + l15];

    float wkf[3], b2init[3];
    #pragma unroll
    for (int nt = 0; nt < 3; ++nt) {
        int n = nt * 16 + l15;
        wkf[nt]    = (n < 40) ? wk[n] : 0.f;
        b2init[nt] = (n < 40) ? b2[n] : 0.f;
    }

    // --- per-wave fused GEMM1 -> sigmoid -> GEMM2 -> score over M-tiles ---
    float4 c0{}, c1{}, c2{}, c3{};
    {
        int arow = wv * 16 + l15;
        if (arow < TT) {
            const float* p = kb + arow * EE + lhi * 8;
            c0 = *reinterpret_cast<const float4*>(p);
            c1 = *reinterpret_cast<const float4*>(p + 4);
            c2 = *reinterpret_cast<const float4*>(p + 32);
            c3 = *reinterpret_cast<const float4*>(p + 36);
        }
    }

    for (int mt = wv; mt < 13; mt += 4) {
        // prefetch next tile's key fragment (overlaps this tile's compute)
        float4 n0 = c0, n1 = c1, n2 = c2, n3 = c3;
        if (mt + 4 < 13) {
            int arow = (mt + 4) * 16 + l15;
            n0 = n1 = n2 = n3 = float4{0.f, 0.f, 0.f, 0.f};
            if (arow < TT) {
                const float* p = kb + arow * EE + lhi * 8;
                n0 = *reinterpret_cast<const float4*>(p);
                n1 = *reinterpret_cast<const float4*>(p + 4);
                n2 = *reinterpret_cast<const float4*>(p + 32);
                n3 = *reinterpret_cast<const float4*>(p + 36);
            }
        }

        // pack A fragments: a0 slot j <-> k = lhi*8+j ; a1 <-> k = 32+lhi*8+j
        bfrag a0, a1;
        a0[0] = (short)f2bf(c0.x); a0[1] = (short)f2bf(c0.y);
        a0[2] = (short)f2bf(c0.z); a0[3] = (short)f2bf(c0.w);
        a0[4] = (short)f2bf(c1.x); a0[5] = (short)f2bf(c1.y);
        a0[6] = (short)f2bf(c1.z); a0[7] = (short)f2bf(c1.w);
        a1[0] = (short)f2bf(c2.x); a1[1] = (short)f2bf(c2.y);
        a1[2] = (short)f2bf(c2.z); a1[3] = (short)f2bf(c2.w);
        a1[4] = (short)f2bf(c3.x); a1[5] = (short)f2bf(c3.y);
        a1[6] = (short)f2bf(c3.z); a1[7] = (short)f2bf(c3.w);

        // GEMM1: h1 = sigmoid(keys @ W1k + qb1)  -> per-wave LDS scratch
        const int hr0 = lhi * 4;
        #pragma unroll
        for (int nt = 0; nt < 5; ++nt) {
            bfrag bA = *reinterpret_cast<const bfrag*>(&b1ls[((nt * 2 + 0) * 64 + lane) * 8]);
            bfrag bB = *reinterpret_cast<const bfrag*>(&b1ls[((nt * 2 + 1) * 64 + lane) * 8]);
            f32x4 acc = { qinit[nt], qinit[nt], qinit[nt], qinit[nt] };
            acc = __builtin_amdgcn_mfma_f32_16x16x32_bf16(a0, bA, acc, 0, 0, 0);
            acc = __builtin_amdgcn_mfma_f32_16x16x32_bf16(a1, bB, acc, 0, 0, 0);
            #pragma unroll
            for (int r = 0; r < 4; ++r)
                h1w[wv][hr0 + r][nt * 16 + l15] = f2bf(sigmoid_fast(acc[r]));
        }

        // GEMM2 A fragments from this wave's scratch (intra-wave lgkmcnt ordering only)
        const u16* ab = &h1w[wv][l15][lhi * 8];
        bfrag x0 = *reinterpret_cast<const bfrag*>(ab);
        bfrag x1 = *reinterpret_cast<const bfrag*>(ab + 32);
        bfrag x2 = *reinterpret_cast<const bfrag*>(ab + 64);

        f32x4 cc[3];
        #pragma unroll
        for (int nt = 0; nt < 3; ++nt) {
            bfrag b0 = *reinterpret_cast<const bfrag*>(&b2ls[((nt * 3 + 0) * 64 + lane) * 8]);
            bfrag b1f = *reinterpret_cast<const bfrag*>(&b2ls[((nt * 3 + 1) * 64 + lane) * 8]);
            bfrag b2f = *reinterpret_cast<const bfrag*>(&b2ls[((nt * 3 + 2) * 64 + lane) * 8]);
            f32x4 c = { b2init[nt], b2init[nt], b2init[nt], b2init[nt] };
            c = __builtin_amdgcn_mfma_f32_16x16x32_bf16(x0, b0, c, 0, 0, 0);
            c = __builtin_amdgcn_mfma_f32_16x16x32_bf16(x1, b1f, c, 0, 0, 0);
            c = __builtin_amdgcn_mfma_f32_16x16x32_bf16(x2, b2f, c, 0, 0, 0);
            cc[nt] = c;
        }

        const int row0 = mt * 16 + lhi * 4;
        #pragma unroll
        for (int r = 0; r < 4; ++r) {
            float p = sigmoid_fast(cc[0][r]) * wkf[0]
                    + sigmoid_fast(cc[1][r]) * wkf[1]
                    + sigmoid_fast(cc[2][r]) * wkf[2];
            p += __shfl_xor(p, 1);
            p += __shfl_xor(p, 2);
            p += __shfl_xor(p, 4);
            p += __shfl_xor(p, 8);
            if (l15 == 0) {
                int row = row0 + r;
                sw[row] = (row < len) ? (p + biass) : NEG;
            }
        }

        c0 = n0; c1 = n1; c2 = n2; c3 = n3;
    }
    __syncthreads();   // barrier 2: all scores in sw

    // --- masked softmax over T=200 (len==0 -> uniform, matches ref) ---
    if (tid < 64) {
        float m = sw[tid];
        for (int t = tid + 64; t < TT; t += 64) m = fmaxf(m, sw[t]);
        #pragma unroll
        for (int off = 32; off; off >>= 1) m = fmaxf(m, __shfl_down(m, off));
        if (tid == 0) sred[0] = m;
    }
    __syncthreads();
    const float m = sred[0];
    if (tid < TT) sw[tid] = __expf(sw[tid] - m);
    __syncthreads();
    if (tid < 64) {
        float s = 0.f;
        for (int t = tid; t < TT; t += 64) s += sw[t];
        #pragma unroll
        for (int off = 32; off; off >>= 1) s += __shfl_down(s, off);
        if (tid == 0) sred[1] = s;
    }
    __syncthreads();
    const float inv = __builtin_amdgcn_rcpf(sred[1]);

    // --- weighted-sum pooling straight from global keys (f32, coalesced, L2/L3-hot) ---
    float acc = 0.f;
    for (int t = wv; t < TT; t += 4)
        acc = fmaf(sw[t], kb[t * EE + lane], acc);
    partial[wv][lane] = acc;
    __syncthreads();
    if (tid < EE)
        out[(size_t)b * EE + tid] =
            (partial[0][tid] + partial[1][tid] + partial[2][tid] + partial[3][tid]) * inv;
}

extern "C" void kernel_launch(void* const* d_in, const int* in_sizes, int n_in,
                              void* d_out, int out_size, void* d_ws, size_t ws_size,
                              hipStream_t stream) {
    const float* queries = (const float*)d_in[0];
    const float* keys    = (const float*)d_in[1];
    const int*   klen    = (const int*)d_in[2];
    const float* W1      = (const float*)d_in[3];
    const float* b1      = (const float*)d_in[4];
    const float* W2      = (const float*)d_in[5];
    const float* b2      = (const float*)d_in[6];
    const float* wk      = (const float*)d_in[7];
    const float* bias    = (const float*)d_in[8];
    float* out           = (float*)d_out;

    u16* B1f = (u16*)d_ws;
    u16* B2f = (u16*)((char*)d_ws + 10240);

    prep_frags<<<20, 256, 0, stream>>>(W1, W2, B1f, B2f);
    din_mfma<<<4096, 256, 0, stream>>>(queries, keys, klen, W1, b1, b2, wk, bias,
                                       B1f, B2f, out);
}

// Round 4
// 194.201 us; speedup vs baseline: 1.1281x; 1.1281x over previous
//
#include <hip/hip_runtime.h>
#include <hip/hip_bf16.h>

#define TT 200
#define EE 64
#define H1S 104   // u16 stride of per-wave h1 scratch (208B rows; 2-way banks = free)

typedef unsigned short u16;
typedef unsigned int u32;
typedef __attribute__((ext_vector_type(8))) short bfrag;   // 8 bf16 in 4 VGPRs
typedef __attribute__((ext_vector_type(4))) float f32x4;

__device__ __forceinline__ u16 f2bf(float f) {
    __hip_bfloat16 h(f);                       // RNE HW cvt
    return __builtin_bit_cast(u16, h);
}
__device__ __forceinline__ float sigmoid_fast(float x) {
    return __builtin_amdgcn_rcpf(1.0f + __expf(-x));
}

// Pre-pack W1k (rows 64..127 of W1) and W2 into MFMA B-fragment order.
// Slot bijection (must match A-frag construction in main kernel):
//   k = ks*32 + (lane>>4)*8 + j ,  n = nt*16 + (lane&15)
__global__ void prep_frags(const float* __restrict__ W1, const float* __restrict__ W2,
                           u16* __restrict__ B1f, u16* __restrict__ B2f) {
    int idx = blockIdx.x * 256 + threadIdx.x;
    if (idx < 5 * 2 * 64 * 8) {  // GEMM1: K=64 (2 ks), N=80 (5 nt)
        int j = idx & 7, l = (idx >> 3) & 63, ks = (idx >> 9) & 1, nt = idx >> 10;
        int k = ks * 32 + ((l >> 4) << 3) + j;
        int n = nt * 16 + (l & 15);
        B1f[idx] = f2bf(W1[(64 + k) * 80 + n]);
    }
    if (idx < 3 * 3 * 64 * 8) {  // GEMM2: K=96 pad (3 ks), N=48 pad (3 nt)
        int j = idx & 7, l = (idx >> 3) & 63, ks = (idx >> 9) % 3, nt = idx / 1536;
        int k = ks * 32 + ((l >> 4) << 3) + j;
        int n = nt * 16 + (l & 15);
        B2f[idx] = (k < 80 && n < 40) ? f2bf(W2[k * 40 + n]) : (u16)0;
    }
}

// One batch per WAVE. 4 waves/block, grid 1024 = 4 blocks/CU exactly.
// Online-softmax fused pooling: keys read from HBM exactly once.
__global__ __launch_bounds__(256, 4) void din_mfma(
    const float* __restrict__ queries,     // (B,1,64)
    const float* __restrict__ keys,        // (B,200,64)
    const int*   __restrict__ keys_length, // (B,1)
    const float* __restrict__ W1,          // (128,80)
    const float* __restrict__ b1,          // (80)
    const float* __restrict__ b2,          // (40)
    const float* __restrict__ wk,          // (40)
    const float* __restrict__ bias,        // (1)
    const u16*   __restrict__ B1f,
    const u16*   __restrict__ B2f,
    float* __restrict__ out)               // (B,1,64)
{
    __shared__ __align__(16) u16 b1ls[5 * 2 * 64 * 8];   // 10240 B
    __shared__ __align__(16) u16 b2ls[3 * 3 * 64 * 8];   //  9216 B
    __shared__ __align__(16) u16 h1w[4][16][H1S];        // per-wave h1 scratch, 13312 B
    __shared__ __align__(16) float ew[4][16];            // per-wave tile weights

    const int tid  = threadIdx.x;
    const int lane = tid & 63;
    const int wv   = tid >> 6;
    const int l15  = lane & 15;
    const int lhi  = lane >> 4;
    const int b    = blockIdx.x * 4 + wv;   // this wave's batch

    const float* kb = keys + (size_t)b * (TT * EE);
    const float* q  = queries + (size_t)b * EE;
    const int len   = keys_length[b];
    const float biass = bias[0];
    const float NEG = -4294967296.0f;       // ref's mask value

    // --- stage B fragments to LDS (coalesced 16B) ---
    for (int c = tid; c < 640; c += 256)
        *reinterpret_cast<float4*>(&b1ls[c * 8]) = reinterpret_cast<const float4*>(B1f)[c];
    for (int c = tid; c < 576; c += 256)
        *reinterpret_cast<float4*>(&b2ls[c * 8]) = reinterpret_cast<const float4*>(B2f)[c];
    // zero this wave's h1 pad cols 80..95 (read as k-pad zeros in GEMM2)
    *reinterpret_cast<unsigned long long*>(&h1w[wv][lane >> 2][80 + (lane & 3) * 4]) = 0ULL;

    // --- per-wave qb1 = q @ W1[0:64] + b1 (lane j owns col j; 16 lanes also cols 64..79) ---
    float v0 = b1[lane];
    #pragma unroll 8
    for (int i = 0; i < EE; ++i)
        v0 = fmaf(q[i], W1[i * 80 + lane], v0);
    float v1 = 0.f;
    if (lane < 16) {
        v1 = b1[64 + lane];
        #pragma unroll 8
        for (int i = 0; i < EE; ++i)
            v1 = fmaf(q[i], W1[i * 80 + 64 + lane], v1);
    }
    float qinit[5];
    #pragma unroll
    for (int nt = 0; nt < 4; ++nt) qinit[nt] = __shfl(v0, nt * 16 + l15);
    qinit[4] = __shfl(v1, l15);

    float wkf[3], b2init[3];
    #pragma unroll
    for (int nt = 0; nt < 3; ++nt) {
        int n = nt * 16 + l15;
        wkf[nt]    = (n < 40) ? wk[n] : 0.f;
        b2init[nt] = (n < 40) ? b2[n] : 0.f;
    }

    __syncthreads();   // the ONLY block barrier: b1ls/b2ls ready

    // --- online-softmax state ---
    float acc[16];
    #pragma unroll
    for (int j = 0; j < 16; ++j) acc[j] = 0.f;
    float m = -INFINITY, Z = 0.f;

    auto loadk = [&](int mt, float4& d0, float4& d1, float4& d2, float4& d3) {
        int arow = mt * 16 + l15;
        d0 = d1 = d2 = d3 = make_float4(0.f, 0.f, 0.f, 0.f);
        if (arow < TT) {
            const float* p = kb + arow * EE + lhi * 8;
            d0 = *reinterpret_cast<const float4*>(p);
            d1 = *reinterpret_cast<const float4*>(p + 4);
            d2 = *reinterpret_cast<const float4*>(p + 32);
            d3 = *reinterpret_cast<const float4*>(p + 36);
        }
    };

    float4 c0, c1, c2, c3;
    loadk(0, c0, c1, c2, c3);

    for (int mt = 0; mt < 13; ++mt) {
        // prefetch next tile (overlaps this tile's compute)
        float4 n0, n1, n2, n3;
        if (mt < 12) loadk(mt + 1, n0, n1, n2, n3);
        else n0 = n1 = n2 = n3 = make_float4(0.f, 0.f, 0.f, 0.f);

        // pack A fragments: a0 slot j <-> k = lhi*8+j ; a1 <-> k = 32+lhi*8+j
        bfrag a0, a1;
        a0[0] = (short)f2bf(c0.x); a0[1] = (short)f2bf(c0.y);
        a0[2] = (short)f2bf(c0.z); a0[3] = (short)f2bf(c0.w);
        a0[4] = (short)f2bf(c1.x); a0[5] = (short)f2bf(c1.y);
        a0[6] = (short)f2bf(c1.z); a0[7] = (short)f2bf(c1.w);
        a1[0] = (short)f2bf(c2.x); a1[1] = (short)f2bf(c2.y);
        a1[2] = (short)f2bf(c2.z); a1[3] = (short)f2bf(c2.w);
        a1[4] = (short)f2bf(c3.x); a1[5] = (short)f2bf(c3.y);
        a1[6] = (short)f2bf(c3.z); a1[7] = (short)f2bf(c3.w);

        // GEMM1: h1 = sigmoid(keys @ W1k + qb1) -> per-wave LDS scratch
        #pragma unroll
        for (int nt = 0; nt < 5; ++nt) {
            bfrag bA = *reinterpret_cast<const bfrag*>(&b1ls[((nt * 2 + 0) * 64 + lane) * 8]);
            bfrag bB = *reinterpret_cast<const bfrag*>(&b1ls[((nt * 2 + 1) * 64 + lane) * 8]);
            f32x4 h = { qinit[nt], qinit[nt], qinit[nt], qinit[nt] };
            h = __builtin_amdgcn_mfma_f32_16x16x32_bf16(a0, bA, h, 0, 0, 0);
            h = __builtin_amdgcn_mfma_f32_16x16x32_bf16(a1, bB, h, 0, 0, 0);
            #pragma unroll
            for (int r = 0; r < 4; ++r)
                h1w[wv][lhi * 4 + r][nt * 16 + l15] = f2bf(sigmoid_fast(h[r]));
        }

        // GEMM2 A-frags from this wave's scratch (same-wave DS ordering, no barrier)
        const u16* ab = &h1w[wv][l15][lhi * 8];
        bfrag x0 = *reinterpret_cast<const bfrag*>(ab);
        bfrag x1 = *reinterpret_cast<const bfrag*>(ab + 32);
        bfrag x2 = *reinterpret_cast<const bfrag*>(ab + 64);

        // GEMM2 + fold score partials on the fly (no cc[3] array -> lower VGPR peak)
        float p0 = 0.f, p1 = 0.f, p2 = 0.f, p3 = 0.f;
        #pragma unroll
        for (int nt = 0; nt < 3; ++nt) {
            bfrag w0 = *reinterpret_cast<const bfrag*>(&b2ls[((nt * 3 + 0) * 64 + lane) * 8]);
            bfrag w1 = *reinterpret_cast<const bfrag*>(&b2ls[((nt * 3 + 1) * 64 + lane) * 8]);
            bfrag w2 = *reinterpret_cast<const bfrag*>(&b2ls[((nt * 3 + 2) * 64 + lane) * 8]);
            f32x4 c = { b2init[nt], b2init[nt], b2init[nt], b2init[nt] };
            c = __builtin_amdgcn_mfma_f32_16x16x32_bf16(x0, w0, c, 0, 0, 0);
            c = __builtin_amdgcn_mfma_f32_16x16x32_bf16(x1, w1, c, 0, 0, 0);
            c = __builtin_amdgcn_mfma_f32_16x16x32_bf16(x2, w2, c, 0, 0, 0);
            float wf = wkf[nt];
            p0 = fmaf(sigmoid_fast(c[0]), wf, p0);
            p1 = fmaf(sigmoid_fast(c[1]), wf, p1);
            p2 = fmaf(sigmoid_fast(c[2]), wf, p2);
            p3 = fmaf(sigmoid_fast(c[3]), wf, p3);
        }
        // reduce over the 16-lane n-groups -> all lanes hold scores of rows lhi*4+r
        p0 += __shfl_xor(p0, 1); p0 += __shfl_xor(p0, 2); p0 += __shfl_xor(p0, 4); p0 += __shfl_xor(p0, 8);
        p1 += __shfl_xor(p1, 1); p1 += __shfl_xor(p1, 2); p1 += __shfl_xor(p1, 4); p1 += __shfl_xor(p1, 8);
        p2 += __shfl_xor(p2, 1); p2 += __shfl_xor(p2, 2); p2 += __shfl_xor(p2, 4); p2 += __shfl_xor(p2, 8);
        p3 += __shfl_xor(p3, 1); p3 += __shfl_xor(p3, 2); p3 += __shfl_xor(p3, 4); p3 += __shfl_xor(p3, 8);

        const int rb = mt * 16 + lhi * 4;
        float s0 = (rb + 0 < len) ? p0 + biass : ((rb + 0 < TT) ? NEG : -INFINITY);
        float s1 = (rb + 1 < len) ? p1 + biass : ((rb + 1 < TT) ? NEG : -INFINITY);
        float s2 = (rb + 2 < len) ? p2 + biass : ((rb + 2 < TT) ? NEG : -INFINITY);
        float s3 = (rb + 3 < len) ? p3 + biass : ((rb + 3 < TT) ? NEG : -INFINITY);

        // online softmax update (wave-uniform m, Z)
        float tmax = fmaxf(fmaxf(s0, s1), fmaxf(s2, s3));
        tmax = fmaxf(tmax, __shfl_xor(tmax, 16));
        tmax = fmaxf(tmax, __shfl_xor(tmax, 32));
        if (tmax > m) {
            float sc = __expf(m - tmax);   // first tile: exp(-inf)=0
            Z *= sc;
            #pragma unroll
            for (int j = 0; j < 16; ++j) acc[j] *= sc;
            m = tmax;
        }
        float e0 = __expf(s0 - m), e1 = __expf(s1 - m);
        float e2 = __expf(s2 - m), e3 = __expf(s3 - m);
        float zs = (e0 + e1) + (e2 + e3);
        zs += __shfl_xor(zs, 16);
        zs += __shfl_xor(zs, 32);
        Z += zs;

        // distribute per-row weights to key-owning lanes (row = l15) via per-wave LDS
        if (l15 == 0)
            *reinterpret_cast<float4*>(&ew[wv][lhi * 4]) = make_float4(e0, e1, e2, e3);
        float wgt = ew[wv][l15];

        // fused pooling: acc += w * key (key already in registers!)
        acc[0]  = fmaf(wgt, c0.x, acc[0]);  acc[1]  = fmaf(wgt, c0.y, acc[1]);
        acc[2]  = fmaf(wgt, c0.z, acc[2]);  acc[3]  = fmaf(wgt, c0.w, acc[3]);
        acc[4]  = fmaf(wgt, c1.x, acc[4]);  acc[5]  = fmaf(wgt, c1.y, acc[5]);
        acc[6]  = fmaf(wgt, c1.z, acc[6]);  acc[7]  = fmaf(wgt, c1.w, acc[7]);
        acc[8]  = fmaf(wgt, c2.x, acc[8]);  acc[9]  = fmaf(wgt, c2.y, acc[9]);
        acc[10] = fmaf(wgt, c2.z, acc[10]); acc[11] = fmaf(wgt, c2.w, acc[11]);
        acc[12] = fmaf(wgt, c3.x, acc[12]); acc[13] = fmaf(wgt, c3.y, acc[13]);
        acc[14] = fmaf(wgt, c3.z, acc[14]); acc[15] = fmaf(wgt, c3.w, acc[15]);

        c0 = n0; c1 = n1; c2 = n2; c3 = n3;
    }

    // --- reduce acc across the 16 row-lanes; lanes l15==0 hold this batch's output ---
    #pragma unroll
    for (int j = 0; j < 16; ++j) {
        acc[j] += __shfl_xor(acc[j], 1);
        acc[j] += __shfl_xor(acc[j], 2);
        acc[j] += __shfl_xor(acc[j], 4);
        acc[j] += __shfl_xor(acc[j], 8);
    }
    if (l15 == 0) {
        float inv = __builtin_amdgcn_rcpf(Z);
        float* ob = out + (size_t)b * EE + lhi * 8;
        float4 o0 = { acc[0] * inv,  acc[1] * inv,  acc[2] * inv,  acc[3] * inv };
        float4 o1 = { acc[4] * inv,  acc[5] * inv,  acc[6] * inv,  acc[7] * inv };
        float4 o2 = { acc[8] * inv,  acc[9] * inv,  acc[10] * inv, acc[11] * inv };
        float4 o3 = { acc[12] * inv, acc[13] * inv, acc[14] * inv, acc[15] * inv };
        *reinterpret_cast<float4*>(ob)      = o0;
        *reinterpret_cast<float4*>(ob + 4)  = o1;
        *reinterpret_cast<float4*>(ob + 32) = o2;
        *reinterpret_cast<float4*>(ob + 36) = o3;
    }
}

extern "C" void kernel_launch(void* const* d_in, const int* in_sizes, int n_in,
                              void* d_out, int out_size, void* d_ws, size_t ws_size,
                              hipStream_t stream) {
    const float* queries = (const float*)d_in[0];
    const float* keys    = (const float*)d_in[1];
    const int*   klen    = (const int*)d_in[2];
    const float* W1      = (const float*)d_in[3];
    const float* b1      = (const float*)d_in[4];
    const float* W2      = (const float*)d_in[5];
    const float* b2      = (const float*)d_in[6];
    const float* wk      = (const float*)d_in[7];
    const float* bias    = (const float*)d_in[8];
    float* out           = (float*)d_out;

    u16* B1f = (u16*)d_ws;
    u16* B2f = (u16*)((char*)d_ws + 10240);

    prep_frags<<<20, 256, 0, stream>>>(W1, W2, B1f, B2f);
    din_mfma<<<1024, 256, 0, stream>>>(queries, keys, klen, W1, b1, b2, wk, bias,
                                       B1f, B2f, out);
}

// Round 5
// 79.324 us; speedup vs baseline: 2.7618x; 2.4482x over previous
//
#include <hip/hip_runtime.h>
#include <hip/hip_bf16.h>

#define TT 200
#define EE 64
#define H1S 104   // u16 stride of per-wave h1 scratch (208B rows; 2-way banks = free)

typedef unsigned short u16;
typedef unsigned int u32;
typedef __attribute__((ext_vector_type(8))) short bfrag;   // 8 bf16 in 4 VGPRs
typedef __attribute__((ext_vector_type(4))) float f32x4;

__device__ __forceinline__ u16 f2bf(float f) {
    __hip_bfloat16 h(f);                       // RNE HW cvt
    return __builtin_bit_cast(u16, h);
}
__device__ __forceinline__ float bf2f(u16 h) {
    return __uint_as_float(((u32)h) << 16);
}
__device__ __forceinline__ float sigmoid_fast(float x) {
    return __builtin_amdgcn_rcpf(1.0f + __expf(-x));
}

// Pre-pack W1k (rows 64..127 of W1) and W2 into MFMA B-fragment order, and
// W1q^T (cols x rows, f32) for the per-wave qb1 dot products.
// Slot bijection (must match A-frag construction in main kernel):
//   k = ks*32 + (lane>>4)*8 + j ,  n = nt*16 + (lane&15)
__global__ void prep_frags(const float* __restrict__ W1, const float* __restrict__ W2,
                           u16* __restrict__ B1f, u16* __restrict__ B2f,
                           float* __restrict__ W1qT) {
    int idx = blockIdx.x * 256 + threadIdx.x;
    if (idx < 5 * 2 * 64 * 8) {  // GEMM1: K=64 (2 ks), N=80 (5 nt)
        int j = idx & 7, l = (idx >> 3) & 63, ks = (idx >> 9) & 1, nt = idx >> 10;
        int k = ks * 32 + ((l >> 4) << 3) + j;
        int n = nt * 16 + (l & 15);
        B1f[idx] = f2bf(W1[(64 + k) * 80 + n]);
    }
    if (idx < 3 * 3 * 64 * 8) {  // GEMM2: K=96 pad (3 ks), N=48 pad (3 nt)
        int j = idx & 7, l = (idx >> 3) & 63, ks = (idx >> 9) % 3, nt = idx / 1536;
        int k = ks * 32 + ((l >> 4) << 3) + j;
        int n = nt * 16 + (l & 15);
        B2f[idx] = (k < 80 && n < 40) ? f2bf(W2[k * 40 + n]) : (u16)0;
    }
    if (idx < 80 * 64) {         // W1qT[c][i] = W1[i][c] for query half (rows 0..63)
        int c = idx >> 6, i = idx & 63;
        W1qT[idx] = W1[i * 80 + c];
    }
}

// One batch per WAVE. 4 waves/block, grid 1024.
// Online-softmax fused pooling: keys read from HBM exactly once.
__global__ __launch_bounds__(256, 2) void din_mfma(
    const float* __restrict__ queries,     // (B,1,64)
    const float* __restrict__ keys,        // (B,200,64)
    const int*   __restrict__ keys_length, // (B,1)
    const float* __restrict__ b1,          // (80)
    const float* __restrict__ b2,          // (40)
    const float* __restrict__ wk,          // (40)
    const float* __restrict__ bias,        // (1)
    const u16*   __restrict__ B1f,
    const u16*   __restrict__ B2f,
    const float* __restrict__ W1qT,        // (80,64) = W1[:64]^T
    float* __restrict__ out)               // (B,1,64)
{
    __shared__ __align__(16) u16 b1ls[5 * 2 * 64 * 8];   // 10240 B
    __shared__ __align__(16) u16 b2ls[3 * 3 * 64 * 8];   //  9216 B
    __shared__ __align__(16) u16 h1w[4][16][H1S];        // per-wave h1 scratch, 13312 B
    __shared__ __align__(16) float ew[4][16];            // per-wave tile weights

    const int tid  = threadIdx.x;
    const int lane = tid & 63;
    const int wv   = tid >> 6;
    const int l15  = lane & 15;
    const int lhi  = lane >> 4;
    const int b    = blockIdx.x * 4 + wv;   // this wave's batch

    const float* kb = keys + (size_t)b * (TT * EE);
    const float* q  = queries + (size_t)b * EE;
    const int len   = keys_length[b];
    const float biass = bias[0];
    const float NEG = -4294967296.0f;       // ref's mask value

    // --- stage B fragments to LDS (coalesced 16B) ---
    for (int c = tid; c < 640; c += 256)
        *reinterpret_cast<float4*>(&b1ls[c * 8]) = reinterpret_cast<const float4*>(B1f)[c];
    for (int c = tid; c < 576; c += 256)
        *reinterpret_cast<float4*>(&b2ls[c * 8]) = reinterpret_cast<const float4*>(B2f)[c];
    // zero this wave's h1 pad cols 80..95 (read as k-pad zeros in GEMM2)
    *reinterpret_cast<unsigned long long*>(&h1w[wv][lane >> 2][80 + (lane & 3) * 4]) = 0ULL;

    // --- per-wave qb1 = q @ W1[0:64] + b1, via W1qT (contiguous per-lane rows) ---
    float v0 = b1[lane];
    {
        const float* wq = W1qT + lane * 64;
        #pragma unroll
        for (int i = 0; i < EE; i += 4) {
            float4 w = *reinterpret_cast<const float4*>(wq + i);
            float4 qv = *reinterpret_cast<const float4*>(q + i);
            v0 = fmaf(qv.x, w.x, v0); v0 = fmaf(qv.y, w.y, v0);
            v0 = fmaf(qv.z, w.z, v0); v0 = fmaf(qv.w, w.w, v0);
        }
    }
    float v1 = 0.f;
    if (lane < 16) {
        v1 = b1[64 + lane];
        const float* wq = W1qT + (64 + lane) * 64;
        #pragma unroll
        for (int i = 0; i < EE; i += 4) {
            float4 w = *reinterpret_cast<const float4*>(wq + i);
            float4 qv = *reinterpret_cast<const float4*>(q + i);
            v1 = fmaf(qv.x, w.x, v1); v1 = fmaf(qv.y, w.y, v1);
            v1 = fmaf(qv.z, w.z, v1); v1 = fmaf(qv.w, w.w, v1);
        }
    }
    float qinit[5];
    #pragma unroll
    for (int nt = 0; nt < 4; ++nt) qinit[nt] = __shfl(v0, nt * 16 + l15);
    qinit[4] = __shfl(v1, l15);

    float wkf[3], b2init[3];
    #pragma unroll
    for (int nt = 0; nt < 3; ++nt) {
        int n = nt * 16 + l15;
        wkf[nt]    = (n < 40) ? wk[n] : 0.f;
        b2init[nt] = (n < 40) ? b2[n] : 0.f;
    }

    __syncthreads();   // the ONLY block barrier: b1ls/b2ls ready

    // --- online-softmax state ---
    float acc[16];
    #pragma unroll
    for (int j = 0; j < 16; ++j) acc[j] = 0.f;
    float m = -INFINITY, Z = 0.f;

    auto loadk = [&](int mt, float4& d0, float4& d1, float4& d2, float4& d3) {
        int arow = mt * 16 + l15;
        d0 = d1 = d2 = d3 = make_float4(0.f, 0.f, 0.f, 0.f);
        if (arow < TT) {
            const float* p = kb + arow * EE + lhi * 8;
            d0 = *reinterpret_cast<const float4*>(p);
            d1 = *reinterpret_cast<const float4*>(p + 4);
            d2 = *reinterpret_cast<const float4*>(p + 32);
            d3 = *reinterpret_cast<const float4*>(p + 36);
        }
    };
    auto pack8 = [](const float4& x, const float4& y) {
        bfrag r;
        r[0] = (short)f2bf(x.x); r[1] = (short)f2bf(x.y);
        r[2] = (short)f2bf(x.z); r[3] = (short)f2bf(x.w);
        r[4] = (short)f2bf(y.x); r[5] = (short)f2bf(y.y);
        r[6] = (short)f2bf(y.z); r[7] = (short)f2bf(y.w);
        return r;
    };

    // prologue: tile 0 -> fragments (keys live ONLY as bf16 frags; pooling reads frags)
    bfrag a0, a1;
    {
        float4 t0, t1, t2, t3;
        loadk(0, t0, t1, t2, t3);
        a0 = pack8(t0, t1);
        a1 = pack8(t2, t3);
    }

    for (int mt = 0; mt < 13; ++mt) {
        // prefetch next tile (floats stay in flight across this tile's compute)
        float4 n0, n1, n2, n3;
        if (mt < 12) loadk(mt + 1, n0, n1, n2, n3);
        else { n0 = n1 = n2 = n3 = make_float4(0.f, 0.f, 0.f, 0.f); }

        // GEMM1: h1 = sigmoid(keys @ W1k + qb1) -> per-wave LDS scratch
        #pragma unroll
        for (int nt = 0; nt < 5; ++nt) {
            bfrag bA = *reinterpret_cast<const bfrag*>(&b1ls[((nt * 2 + 0) * 64 + lane) * 8]);
            bfrag bB = *reinterpret_cast<const bfrag*>(&b1ls[((nt * 2 + 1) * 64 + lane) * 8]);
            f32x4 h = { qinit[nt], qinit[nt], qinit[nt], qinit[nt] };
            h = __builtin_amdgcn_mfma_f32_16x16x32_bf16(a0, bA, h, 0, 0, 0);
            h = __builtin_amdgcn_mfma_f32_16x16x32_bf16(a1, bB, h, 0, 0, 0);
            #pragma unroll
            for (int r = 0; r < 4; ++r)
                h1w[wv][lhi * 4 + r][nt * 16 + l15] = f2bf(sigmoid_fast(h[r]));
        }

        // GEMM2 A-frags from this wave's scratch (same-wave DS ordering, no barrier)
        const u16* ab = &h1w[wv][l15][lhi * 8];
        bfrag x0 = *reinterpret_cast<const bfrag*>(ab);
        bfrag x1 = *reinterpret_cast<const bfrag*>(ab + 32);
        bfrag x2 = *reinterpret_cast<const bfrag*>(ab + 64);

        // GEMM2 + fold score partials on the fly
        float p0 = 0.f, p1 = 0.f, p2 = 0.f, p3 = 0.f;
        #pragma unroll
        for (int nt = 0; nt < 3; ++nt) {
            bfrag w0 = *reinterpret_cast<const bfrag*>(&b2ls[((nt * 3 + 0) * 64 + lane) * 8]);
            bfrag w1 = *reinterpret_cast<const bfrag*>(&b2ls[((nt * 3 + 1) * 64 + lane) * 8]);
            bfrag w2 = *reinterpret_cast<const bfrag*>(&b2ls[((nt * 3 + 2) * 64 + lane) * 8]);
            f32x4 c = { b2init[nt], b2init[nt], b2init[nt], b2init[nt] };
            c = __builtin_amdgcn_mfma_f32_16x16x32_bf16(x0, w0, c, 0, 0, 0);
            c = __builtin_amdgcn_mfma_f32_16x16x32_bf16(x1, w1, c, 0, 0, 0);
            c = __builtin_amdgcn_mfma_f32_16x16x32_bf16(x2, w2, c, 0, 0, 0);
            float wf = wkf[nt];
            p0 = fmaf(sigmoid_fast(c[0]), wf, p0);
            p1 = fmaf(sigmoid_fast(c[1]), wf, p1);
            p2 = fmaf(sigmoid_fast(c[2]), wf, p2);
            p3 = fmaf(sigmoid_fast(c[3]), wf, p3);
        }
        // reduce over 16-lane n-groups -> all lanes hold scores of rows lhi*4+r
        p0 += __shfl_xor(p0, 1); p0 += __shfl_xor(p0, 2); p0 += __shfl_xor(p0, 4); p0 += __shfl_xor(p0, 8);
        p1 += __shfl_xor(p1, 1); p1 += __shfl_xor(p1, 2); p1 += __shfl_xor(p1, 4); p1 += __shfl_xor(p1, 8);
        p2 += __shfl_xor(p2, 1); p2 += __shfl_xor(p2, 2); p2 += __shfl_xor(p2, 4); p2 += __shfl_xor(p2, 8);
        p3 += __shfl_xor(p3, 1); p3 += __shfl_xor(p3, 2); p3 += __shfl_xor(p3, 4); p3 += __shfl_xor(p3, 8);

        const int rb = mt * 16 + lhi * 4;
        float s0 = (rb + 0 < len) ? p0 + biass : ((rb + 0 < TT) ? NEG : -INFINITY);
        float s1 = (rb + 1 < len) ? p1 + biass : ((rb + 1 < TT) ? NEG : -INFINITY);
        float s2 = (rb + 2 < len) ? p2 + biass : ((rb + 2 < TT) ? NEG : -INFINITY);
        float s3 = (rb + 3 < len) ? p3 + biass : ((rb + 3 < TT) ? NEG : -INFINITY);

        // online softmax update (wave-uniform m, Z)
        float tmax = fmaxf(fmaxf(s0, s1), fmaxf(s2, s3));
        tmax = fmaxf(tmax, __shfl_xor(tmax, 16));
        tmax = fmaxf(tmax, __shfl_xor(tmax, 32));
        if (tmax > m) {
            float sc = __expf(m - tmax);   // first tile: exp(-inf)=0
            Z *= sc;
            #pragma unroll
            for (int j = 0; j < 16; ++j) acc[j] *= sc;
            m = tmax;
        }
        float e0 = __expf(s0 - m), e1 = __expf(s1 - m);
        float e2 = __expf(s2 - m), e3 = __expf(s3 - m);
        float zs = (e0 + e1) + (e2 + e3);
        zs += __shfl_xor(zs, 16);
        zs += __shfl_xor(zs, 32);
        Z += zs;

        // distribute per-row weights to key-owning lanes (row = l15) via per-wave LDS
        if (l15 == 0)
            *reinterpret_cast<float4*>(&ew[wv][lhi * 4]) = make_float4(e0, e1, e2, e3);
        float wgt = ew[wv][l15];

        // fused pooling from the bf16 fragments (key regs already free)
        #pragma unroll
        for (int j = 0; j < 8; ++j) {
            acc[j]     = fmaf(wgt, bf2f((u16)a0[j]), acc[j]);
            acc[8 + j] = fmaf(wgt, bf2f((u16)a1[j]), acc[8 + j]);
        }

        // pack next tile's fragments (loads have had the whole body to land)
        a0 = pack8(n0, n1);
        a1 = pack8(n2, n3);
    }

    // --- reduce acc across the 16 row-lanes; lanes l15==0 hold this batch's output ---
    #pragma unroll
    for (int j = 0; j < 16; ++j) {
        acc[j] += __shfl_xor(acc[j], 1);
        acc[j] += __shfl_xor(acc[j], 2);
        acc[j] += __shfl_xor(acc[j], 4);
        acc[j] += __shfl_xor(acc[j], 8);
    }
    if (l15 == 0) {
        float inv = __builtin_amdgcn_rcpf(Z);
        float* ob = out + (size_t)b * EE + lhi * 8;
        float4 o0 = { acc[0] * inv,  acc[1] * inv,  acc[2] * inv,  acc[3] * inv };
        float4 o1 = { acc[4] * inv,  acc[5] * inv,  acc[6] * inv,  acc[7] * inv };
        float4 o2 = { acc[8] * inv,  acc[9] * inv,  acc[10] * inv, acc[11] * inv };
        float4 o3 = { acc[12] * inv, acc[13] * inv, acc[14] * inv, acc[15] * inv };
        *reinterpret_cast<float4*>(ob)      = o0;
        *reinterpret_cast<float4*>(ob + 4)  = o1;
        *reinterpret_cast<float4*>(ob + 32) = o2;
        *reinterpret_cast<float4*>(ob + 36) = o3;
    }
}

extern "C" void kernel_launch(void* const* d_in, const int* in_sizes, int n_in,
                              void* d_out, int out_size, void* d_ws, size_t ws_size,
                              hipStream_t stream) {
    const float* queries = (const float*)d_in[0];
    const float* keys    = (const float*)d_in[1];
    const int*   klen    = (const int*)d_in[2];
    const float* W1      = (const float*)d_in[3];
    const float* b1      = (const float*)d_in[4];
    const float* W2      = (const float*)d_in[5];
    const float* b2      = (const float*)d_in[6];
    const float* wk      = (const float*)d_in[7];
    const float* bias    = (const float*)d_in[8];
    float* out           = (float*)d_out;

    u16*   B1f  = (u16*)d_ws;                              // 10240 B
    u16*   B2f  = (u16*)((char*)d_ws + 10240);             //  9216 B
    float* W1qT = (float*)((char*)d_ws + 20480);           // 20480 B

    prep_frags<<<20, 256, 0, stream>>>(W1, W2, B1f, B2f, W1qT);
    din_mfma<<<1024, 256, 0, stream>>>(queries, keys, klen, b1, b2, wk, bias,
                                       B1f, B2f, W1qT, out);
}

// Round 6
// 67.513 us; speedup vs baseline: 3.2449x; 1.1749x over previous
//
#include <hip/hip_runtime.h>
#include <hip/hip_bf16.h>

#define TT 200
#define EE 64

typedef unsigned short u16;
typedef unsigned int u32;
typedef __attribute__((ext_vector_type(8))) short bfrag;   // 8 bf16 in 4 VGPRs
typedef __attribute__((ext_vector_type(4))) float f32x4;

__device__ __forceinline__ u16 f2bf(float f) {
    __hip_bfloat16 h(f);                       // RNE HW cvt
    return __builtin_bit_cast(u16, h);
}
__device__ __forceinline__ float bf2f(u16 h) {
    return __uint_as_float(((u32)h) << 16);
}
__device__ __forceinline__ float sigmoid_fast(float x) {
    return __builtin_amdgcn_rcpf(1.0f + __expf(-x));
}

// Pack W1k^T and W2^T into MFMA *A*-fragment order for swapped-operand GEMMs.
// GEMM1 (D1^T = W1k^T x keys^T):  A slot (g=l>>4, ks, j) <-> k = ks*32 + g*8 + j
// GEMM2 (D2^T = W2^T x h1^T): custom bijection matching h1's C-layout residency:
//   idx24 = ks*8+j; idx24<20: (mt5=idx24>>2, r=idx24&3), k = mt5*16 + g*4 + r
__global__ void prep_frags(const float* __restrict__ W1, const float* __restrict__ W2,
                           u16* __restrict__ A1p, u16* __restrict__ A2p,
                           float* __restrict__ W1qT) {
    int idx = blockIdx.x * 256 + threadIdx.x;
    if (idx < 5 * 2 * 64 * 8) {   // 5 m-tiles (h1 cols 80) x 2 k-chunks (E=64)
        int j = idx & 7, l = (idx >> 3) & 63, ks = (idx >> 9) & 1, mt5 = idx >> 10;
        int g = l >> 4, m = mt5 * 16 + (l & 15);
        int k = ks * 32 + g * 8 + j;
        A1p[idx] = f2bf(W1[(64 + k) * 80 + m]);
    }
    if (idx < 3 * 3 * 64 * 8) {   // 3 m-tiles (h2 dim 40->48) x 3 k-chunks (80->96)
        int j = idx & 7, l = (idx >> 3) & 63, ks = (idx >> 9) % 3, m2 = idx / 1536;
        int g = l >> 4, m = m2 * 16 + (l & 15);
        int i24 = ks * 8 + j;
        u16 v = 0;
        if (i24 < 20 && m < 40) {
            int mt5 = i24 >> 2, r = i24 & 3;
            int k = mt5 * 16 + g * 4 + r;
            v = f2bf(W2[k * 40 + m]);
        }
        A2p[idx] = v;
    }
    if (idx < 80 * 64) {          // W1qT[c][i] = W1[i][c], query half
        int c = idx >> 6, i = idx & 63;
        W1qT[idx] = W1[i * 80 + c];
    }
}

#define LOADK(MT, D0, D1, D2, D3) {                                     \
    int arow_ = (MT) * 16 + l15;                                        \
    D0 = D1 = D2 = D3 = make_float4(0.f, 0.f, 0.f, 0.f);                \
    if (arow_ < TT) {                                                   \
        const float* p_ = kb + arow_ * EE + g * 8;                      \
        D0 = *reinterpret_cast<const float4*>(p_);                      \
        D1 = *reinterpret_cast<const float4*>(p_ + 4);                  \
        D2 = *reinterpret_cast<const float4*>(p_ + 32);                 \
        D3 = *reinterpret_cast<const float4*>(p_ + 36);                 \
    } }

#define PACK(A, X, Y) {                                                 \
    A[0] = (short)f2bf(X.x); A[1] = (short)f2bf(X.y);                   \
    A[2] = (short)f2bf(X.z); A[3] = (short)f2bf(X.w);                   \
    A[4] = (short)f2bf(Y.x); A[5] = (short)f2bf(Y.y);                   \
    A[6] = (short)f2bf(Y.z); A[7] = (short)f2bf(Y.w); }

// One tile: uses frags a0/a1 (tile MT); issues loads for MT+2 into Q*;
// at the end packs P* (floats of tile MT+1) into a0/a1.
#define BODY(MT, P0, P1, P2, P3, Q0, Q1, Q2, Q3) {                      \
    if ((MT) + 2 < 13) { LOADK((MT) + 2, Q0, Q1, Q2, Q3); }             \
    /* GEMM1 swapped: lane (g,l15) gets h1pre[t=l15][n=mt5*16+g*4+r] */ \
    f32x4 d_[5];                                                        \
    _Pragma("unroll")                                                   \
    for (int mt5 = 0; mt5 < 5; ++mt5) {                                 \
        f32x4 c_ = { qinit[mt5][0], qinit[mt5][1],                      \
                     qinit[mt5][2], qinit[mt5][3] };                    \
        c_ = __builtin_amdgcn_mfma_f32_16x16x32_bf16(w1f[mt5][0], a0, c_, 0, 0, 0); \
        c_ = __builtin_amdgcn_mfma_f32_16x16x32_bf16(w1f[mt5][1], a1, c_, 0, 0, 0); \
        d_[mt5] = c_;                                                   \
    }                                                                   \
    /* sigmoid -> GEMM2 B-frags in registers (idx = ks*8+j -> (mt5,r)) */ \
    bfrag xb0, xb1, xb2;                                                \
    _Pragma("unroll")                                                   \
    for (int j = 0; j < 8; ++j) {                                       \
        xb0[j] = (short)f2bf(sigmoid_fast(d_[j >> 2][j & 3]));          \
        xb1[j] = (short)f2bf(sigmoid_fast(d_[(8 + j) >> 2][(8 + j) & 3])); \
        xb2[j] = (short)((16 + j) < 20                                  \
                    ? f2bf(sigmoid_fast(d_[(16 + j) >> 2][(16 + j) & 3])) : 0); \
    }                                                                   \
    /* GEMM2 swapped + wk-dot folded; lane col = t-row = l15 */         \
    float p_ = 0.f;                                                     \
    _Pragma("unroll")                                                   \
    for (int m2 = 0; m2 < 3; ++m2) {                                    \
        f32x4 c_ = { b2v[m2][0], b2v[m2][1], b2v[m2][2], b2v[m2][3] };  \
        c_ = __builtin_amdgcn_mfma_f32_16x16x32_bf16(w2f[m2][0], xb0, c_, 0, 0, 0); \
        c_ = __builtin_amdgcn_mfma_f32_16x16x32_bf16(w2f[m2][1], xb1, c_, 0, 0, 0); \
        c_ = __builtin_amdgcn_mfma_f32_16x16x32_bf16(w2f[m2][2], xb2, c_, 0, 0, 0); \
        _Pragma("unroll")                                               \
        for (int rr = 0; rr < 4; ++rr)                                  \
            p_ = fmaf(sigmoid_fast(c_[rr]), wkv[m2][rr], p_);           \
    }                                                                   \
    p_ += __shfl_xor(p_, 16); p_ += __shfl_xor(p_, 32);                 \
    int row_ = (MT) * 16 + l15;                                         \
    float s_ = (row_ < len) ? (p_ + biass)                              \
                            : ((row_ < TT) ? NEG : -__builtin_inff());  \
    float t_ = fmaxf(s_, __shfl_xor(s_, 1));                            \
    t_ = fmaxf(t_, __shfl_xor(t_, 2));                                  \
    t_ = fmaxf(t_, __shfl_xor(t_, 4));                                  \
    t_ = fmaxf(t_, __shfl_xor(t_, 8));                                  \
    if (t_ > m) {                                                       \
        float sc_ = __expf(m - t_);                                     \
        Z *= sc_;                                                       \
        _Pragma("unroll")                                               \
        for (int j = 0; j < 16; ++j) acc[j] *= sc_;                     \
        m = t_;                                                         \
    }                                                                   \
    float e_ = __expf(s_ - m);                                          \
    float zs_ = e_ + __shfl_xor(e_, 1);                                 \
    zs_ += __shfl_xor(zs_, 2);                                          \
    zs_ += __shfl_xor(zs_, 4);                                          \
    zs_ += __shfl_xor(zs_, 8);                                          \
    Z += zs_;                                                           \
    /* fused pooling: lane's own row weight e_, keys still in frags */  \
    _Pragma("unroll")                                                   \
    for (int j = 0; j < 8; ++j) {                                       \
        acc[j]     = fmaf(e_, bf2f((u16)a0[j]), acc[j]);                \
        acc[8 + j] = fmaf(e_, bf2f((u16)a1[j]), acc[8 + j]);            \
    }                                                                   \
    PACK(a0, P0, P1); PACK(a1, P2, P3); }

// One batch per WAVE; no LDS, no barriers. 4 waves/block, grid 1024.
__global__ __launch_bounds__(256, 2) void din_mfma(
    const float* __restrict__ queries,     // (B,1,64)
    const float* __restrict__ keys,        // (B,200,64)
    const int*   __restrict__ keys_length, // (B,1)
    const float* __restrict__ b1,          // (80)
    const float* __restrict__ b2,          // (40)
    const float* __restrict__ wk,          // (40)
    const float* __restrict__ bias,        // (1)
    const u16*   __restrict__ A1p,
    const u16*   __restrict__ A2p,
    const float* __restrict__ W1qT,        // (80,64) = W1[:64]^T
    float* __restrict__ out)               // (B,1,64)
{
    const int tid  = threadIdx.x;
    const int lane = tid & 63;
    const int wv   = tid >> 6;
    const int l15  = lane & 15;
    const int g    = lane >> 4;
    const int b    = blockIdx.x * 4 + wv;

    const float* kb = keys + (size_t)b * (TT * EE);
    const float* q  = queries + (size_t)b * EE;
    const int len   = keys_length[b];
    const float biass = bias[0];
    const float NEG = -4294967296.0f;

    // hoisted weight A-fragments (global, read once per wave, L2-hot)
    bfrag w1f[5][2];
    #pragma unroll
    for (int mt5 = 0; mt5 < 5; ++mt5)
        #pragma unroll
        for (int ks = 0; ks < 2; ++ks)
            w1f[mt5][ks] = *reinterpret_cast<const bfrag*>(A1p + (((mt5 * 2 + ks) * 64 + lane) << 3));
    bfrag w2f[3][3];
    #pragma unroll
    for (int m2 = 0; m2 < 3; ++m2)
        #pragma unroll
        for (int ks = 0; ks < 3; ++ks)
            w2f[m2][ks] = *reinterpret_cast<const bfrag*>(A2p + (((m2 * 3 + ks) * 64 + lane) << 3));

    // per-lane wk / b2 for D2 rows m = m2*16 + g*4 + rr
    float wkv[3][4], b2v[3][4];
    #pragma unroll
    for (int m2 = 0; m2 < 3; ++m2)
        #pragma unroll
        for (int rr = 0; rr < 4; ++rr) {
            int mm = m2 * 16 + g * 4 + rr;
            wkv[m2][rr] = (mm < 40) ? wk[mm] : 0.f;
            b2v[m2][rr] = (mm < 40) ? b2[mm] : 0.f;
        }

    // qb1 = q @ W1[:64] + b1 (lane c owns col c via W1qT; cols 64..79 on lanes 0..15)
    float v0 = b1[lane];
    {
        const float* wq = W1qT + lane * 64;
        #pragma unroll
        for (int i = 0; i < EE; i += 4) {
            float4 w = *reinterpret_cast<const float4*>(wq + i);
            float4 qv = *reinterpret_cast<const float4*>(q + i);
            v0 = fmaf(qv.x, w.x, v0); v0 = fmaf(qv.y, w.y, v0);
            v0 = fmaf(qv.z, w.z, v0); v0 = fmaf(qv.w, w.w, v0);
        }
    }
    float v1 = 0.f;
    if (lane < 16) {
        v1 = b1[64 + lane];
        const float* wq = W1qT + (64 + lane) * 64;
        #pragma unroll
        for (int i = 0; i < EE; i += 4) {
            float4 w = *reinterpret_cast<const float4*>(wq + i);
            float4 qv = *reinterpret_cast<const float4*>(q + i);
            v1 = fmaf(qv.x, w.x, v1); v1 = fmaf(qv.y, w.y, v1);
            v1 = fmaf(qv.z, w.z, v1); v1 = fmaf(qv.w, w.w, v1);
        }
    }
    // qinit[mt5][r] = qb1[mt5*16 + g*4 + r]  (matches swapped-GEMM1 C-layout rows)
    float qinit[5][4];
    #pragma unroll
    for (int mt5 = 0; mt5 < 4; ++mt5)
        #pragma unroll
        for (int r = 0; r < 4; ++r)
            qinit[mt5][r] = __shfl(v0, mt5 * 16 + g * 4 + r);
    #pragma unroll
    for (int r = 0; r < 4; ++r)
        qinit[4][r] = __shfl(v1, g * 4 + r);

    // online-softmax state
    float acc[16];
    #pragma unroll
    for (int j = 0; j < 16; ++j) acc[j] = 0.f;
    float m = -__builtin_inff(), Z = 0.f;

    // 2-deep key prefetch: loads issued ~2 bodies (>900 cyc) before use
    float4 fa0, fa1, fa2, fa3, fb0, fb1, fb2, fb3;
    LOADK(0, fa0, fa1, fa2, fa3);
    LOADK(1, fb0, fb1, fb2, fb3);
    bfrag a0, a1;
    PACK(a0, fa0, fa1); PACK(a1, fa2, fa3);

    for (int mt = 0; mt < 13; mt += 2) {
        BODY(mt, fb0, fb1, fb2, fb3, fa0, fa1, fa2, fa3);
        if (mt + 1 < 13) BODY(mt + 1, fa0, fa1, fa2, fa3, fb0, fb1, fb2, fb3);
    }

    // reduce pooled features over the 16 t-row lanes; lanes l15==0 write out
    #pragma unroll
    for (int j = 0; j < 16; ++j) {
        acc[j] += __shfl_xor(acc[j], 1);
        acc[j] += __shfl_xor(acc[j], 2);
        acc[j] += __shfl_xor(acc[j], 4);
        acc[j] += __shfl_xor(acc[j], 8);
    }
    if (l15 == 0) {
        float inv = __builtin_amdgcn_rcpf(Z);
        float* ob = out + (size_t)b * EE + g * 8;
        float4 o0 = { acc[0] * inv,  acc[1] * inv,  acc[2] * inv,  acc[3] * inv };
        float4 o1 = { acc[4] * inv,  acc[5] * inv,  acc[6] * inv,  acc[7] * inv };
        float4 o2 = { acc[8] * inv,  acc[9] * inv,  acc[10] * inv, acc[11] * inv };
        float4 o3 = { acc[12] * inv, acc[13] * inv, acc[14] * inv, acc[15] * inv };
        *reinterpret_cast<float4*>(ob)      = o0;
        *reinterpret_cast<float4*>(ob + 4)  = o1;
        *reinterpret_cast<float4*>(ob + 32) = o2;
        *reinterpret_cast<float4*>(ob + 36) = o3;
    }
}

extern "C" void kernel_launch(void* const* d_in, const int* in_sizes, int n_in,
                              void* d_out, int out_size, void* d_ws, size_t ws_size,
                              hipStream_t stream) {
    const float* queries = (const float*)d_in[0];
    const float* keys    = (const float*)d_in[1];
    const int*   klen    = (const int*)d_in[2];
    const float* W1      = (const float*)d_in[3];
    const float* b1      = (const float*)d_in[4];
    const float* W2      = (const float*)d_in[5];
    const float* b2      = (const float*)d_in[6];
    const float* wk      = (const float*)d_in[7];
    const float* bias    = (const float*)d_in[8];
    float* out           = (float*)d_out;

    u16*   A1p  = (u16*)d_ws;                              // 10240 B
    u16*   A2p  = (u16*)((char*)d_ws + 10240);             //  9216 B
    float* W1qT = (float*)((char*)d_ws + 20480);           // 20480 B

    prep_frags<<<20, 256, 0, stream>>>(W1, W2, A1p, A2p, W1qT);
    din_mfma<<<1024, 256, 0, stream>>>(queries, keys, klen, b1, b2, wk, bias,
                                       A1p, A2p, W1qT, out);
}

// Round 7
// 61.517 us; speedup vs baseline: 3.5613x; 1.0975x over previous
//
#include <hip/hip_runtime.h>
#include <hip/hip_bf16.h>

#define TT 200
#define EE 64

typedef unsigned short u16;
typedef unsigned int u32;
typedef __attribute__((ext_vector_type(8))) short bfrag;   // 8 bf16 in 4 VGPRs
typedef __attribute__((ext_vector_type(4))) float f32x4;

__device__ __forceinline__ u16 f2bf(float f) {
    __hip_bfloat16 h(f);                       // RNE HW cvt
    return __builtin_bit_cast(u16, h);
}
__device__ __forceinline__ float bf2f(u16 h) {
    return __uint_as_float(((u32)h) << 16);
}
__device__ __forceinline__ float sigmoid_fast(float x) {
    return __builtin_amdgcn_rcpf(1.0f + __expf(-x));
}

// Pack W1q^T, W1k^T and W2^T into MFMA *A*-fragment order for swapped GEMMs.
// GEMM1/GEMMq: A slot (g=l>>4, ks, j) <-> k = ks*32 + g*8 + j, m = mt5*16 + l15
// GEMM2: custom bijection matching h1's C-layout residency:
//   i24 = ks*8+j; i24<20: (mt5=i24>>2, r=i24&3), k = mt5*16 + g*4 + r
__global__ void prep_frags(const float* __restrict__ W1, const float* __restrict__ W2,
                           u16* __restrict__ A1p, u16* __restrict__ A2p,
                           u16* __restrict__ A1q) {
    int idx = blockIdx.x * 256 + threadIdx.x;
    if (idx < 5 * 2 * 64 * 8) {   // 5 m-tiles (80) x 2 k-chunks (64)
        int j = idx & 7, l = (idx >> 3) & 63, ks = (idx >> 9) & 1, mt5 = idx >> 10;
        int g = l >> 4, m = mt5 * 16 + (l & 15);
        int k = ks * 32 + g * 8 + j;
        A1p[idx] = f2bf(W1[(64 + k) * 80 + m]);   // key half
        A1q[idx] = f2bf(W1[k * 80 + m]);          // query half
    }
    if (idx < 3 * 3 * 64 * 8) {   // 3 m-tiles (40->48) x 3 k-chunks (80->96)
        int j = idx & 7, l = (idx >> 3) & 63, ks = (idx >> 9) % 3, m2 = idx / 1536;
        int g = l >> 4, m = m2 * 16 + (l & 15);
        int i24 = ks * 8 + j;
        u16 v = 0;
        if (i24 < 20 && m < 40) {
            int mt5 = i24 >> 2, r = i24 & 3;
            int k = mt5 * 16 + g * 4 + r;
            v = f2bf(W2[k * 40 + m]);
        }
        A2p[idx] = v;
    }
}

#define LOADK(MT, D0, D1, D2, D3) {                                     \
    int arow_ = (MT) * 16 + l15;                                        \
    D0 = D1 = D2 = D3 = make_float4(0.f, 0.f, 0.f, 0.f);                \
    if (arow_ < TT) {                                                   \
        const float* p_ = kb + arow_ * EE + g * 8;                      \
        D0 = *reinterpret_cast<const float4*>(p_);                      \
        D1 = *reinterpret_cast<const float4*>(p_ + 4);                  \
        D2 = *reinterpret_cast<const float4*>(p_ + 32);                 \
        D3 = *reinterpret_cast<const float4*>(p_ + 36);                 \
    } }

#define PACK(A, X, Y) {                                                 \
    A[0] = (short)f2bf(X.x); A[1] = (short)f2bf(X.y);                   \
    A[2] = (short)f2bf(X.z); A[3] = (short)f2bf(X.w);                   \
    A[4] = (short)f2bf(Y.x); A[5] = (short)f2bf(Y.y);                   \
    A[6] = (short)f2bf(Y.z); A[7] = (short)f2bf(Y.w); }

// One tile: uses frags a0/a1 (tile MT); issues loads for MT+2 into Q*;
// at the end packs P* (floats of tile MT+1) into a0/a1.
#define BODY(MT, P0, P1, P2, P3, Q0, Q1, Q2, Q3) {                      \
    if ((MT) + 2 < 13) { LOADK((MT) + 2, Q0, Q1, Q2, Q3); }             \
    /* GEMM1 swapped: lane (g,l15) gets h1pre[t=l15][m=mt5*16+g*4+r] */ \
    f32x4 d_[5];                                                        \
    _Pragma("unroll")                                                   \
    for (int mt5 = 0; mt5 < 5; ++mt5) {                                 \
        bfrag wA = *reinterpret_cast<const bfrag*>(&w1ls[((mt5 * 2 + 0) * 64 + lane) * 8]); \
        bfrag wB = *reinterpret_cast<const bfrag*>(&w1ls[((mt5 * 2 + 1) * 64 + lane) * 8]); \
        f32x4 c_ = *reinterpret_cast<const f32x4*>(&qils[wv][mt5 * 16 + g * 4]); \
        c_ = __builtin_amdgcn_mfma_f32_16x16x32_bf16(wA, a0, c_, 0, 0, 0); \
        c_ = __builtin_amdgcn_mfma_f32_16x16x32_bf16(wB, a1, c_, 0, 0, 0); \
        d_[mt5] = c_;                                                   \
    }                                                                   \
    /* sigmoid -> GEMM2 B-frags in registers (i24 = ks*8+j -> (mt5,r)) */ \
    bfrag xb0, xb1, xb2;                                                \
    _Pragma("unroll")                                                   \
    for (int j = 0; j < 8; ++j) {                                       \
        xb0[j] = (short)f2bf(sigmoid_fast(d_[j >> 2][j & 3]));          \
        xb1[j] = (short)f2bf(sigmoid_fast(d_[(8 + j) >> 2][(8 + j) & 3])); \
        xb2[j] = (short)((16 + j) < 20                                  \
                    ? f2bf(sigmoid_fast(d_[(16 + j) >> 2][(16 + j) & 3])) : 0); \
    }                                                                   \
    /* GEMM2 swapped + wk-dot folded; lane col = t-row = l15 */         \
    float p_ = 0.f;                                                     \
    _Pragma("unroll")                                                   \
    for (int m2 = 0; m2 < 3; ++m2) {                                    \
        bfrag u0 = *reinterpret_cast<const bfrag*>(&w2ls[((m2 * 3 + 0) * 64 + lane) * 8]); \
        bfrag u1 = *reinterpret_cast<const bfrag*>(&w2ls[((m2 * 3 + 1) * 64 + lane) * 8]); \
        bfrag u2 = *reinterpret_cast<const bfrag*>(&w2ls[((m2 * 3 + 2) * 64 + lane) * 8]); \
        f32x4 c_ = *reinterpret_cast<const f32x4*>(&b2ls[m2 * 16 + g * 4]); \
        c_ = __builtin_amdgcn_mfma_f32_16x16x32_bf16(u0, xb0, c_, 0, 0, 0); \
        c_ = __builtin_amdgcn_mfma_f32_16x16x32_bf16(u1, xb1, c_, 0, 0, 0); \
        c_ = __builtin_amdgcn_mfma_f32_16x16x32_bf16(u2, xb2, c_, 0, 0, 0); \
        f32x4 wv4 = *reinterpret_cast<const f32x4*>(&wkls[m2 * 16 + g * 4]); \
        _Pragma("unroll")                                               \
        for (int rr = 0; rr < 4; ++rr)                                  \
            p_ = fmaf(sigmoid_fast(c_[rr]), wv4[rr], p_);               \
    }                                                                   \
    p_ += __shfl_xor(p_, 16); p_ += __shfl_xor(p_, 32);                 \
    int row_ = (MT) * 16 + l15;                                         \
    float s_ = (row_ < len) ? (p_ + biass)                              \
                            : ((row_ < TT) ? NEG : -__builtin_inff());  \
    float t_ = fmaxf(s_, __shfl_xor(s_, 1));                            \
    t_ = fmaxf(t_, __shfl_xor(t_, 2));                                  \
    t_ = fmaxf(t_, __shfl_xor(t_, 4));                                  \
    t_ = fmaxf(t_, __shfl_xor(t_, 8));                                  \
    if (t_ > m) {                                                       \
        float sc_ = __expf(m - t_);                                     \
        Z *= sc_;                                                       \
        _Pragma("unroll")                                               \
        for (int j = 0; j < 16; ++j) acc[j] *= sc_;                     \
        m = t_;                                                         \
    }                                                                   \
    float e_ = __expf(s_ - m);                                          \
    float zs_ = e_ + __shfl_xor(e_, 1);                                 \
    zs_ += __shfl_xor(zs_, 2);                                          \
    zs_ += __shfl_xor(zs_, 4);                                          \
    zs_ += __shfl_xor(zs_, 8);                                          \
    Z += zs_;                                                           \
    /* fused pooling: lane's own row weight e_, keys still in frags */  \
    _Pragma("unroll")                                                   \
    for (int j = 0; j < 8; ++j) {                                       \
        acc[j]     = fmaf(e_, bf2f((u16)a0[j]), acc[j]);                \
        acc[8 + j] = fmaf(e_, bf2f((u16)a1[j]), acc[8 + j]);            \
    }                                                                   \
    PACK(a0, P0, P1); PACK(a1, P2, P3); }

// One batch per WAVE; weights block-shared in LDS. 4 waves/block, grid 1024.
__global__ __launch_bounds__(256, 2) void din_mfma(
    const float* __restrict__ queries,     // (B,1,64)
    const float* __restrict__ keys,        // (B,200,64)
    const int*   __restrict__ keys_length, // (B,1)
    const float* __restrict__ b1,          // (80)
    const float* __restrict__ b2,          // (40)
    const float* __restrict__ wk,          // (40)
    const float* __restrict__ bias,        // (1)
    const u16*   __restrict__ A1p,
    const u16*   __restrict__ A2p,
    const u16*   __restrict__ A1q,
    float* __restrict__ out)               // (B,1,64)
{
    __shared__ __align__(16) u16 w1ls[5 * 2 * 64 * 8];   // 10240 B
    __shared__ __align__(16) u16 w2ls[3 * 3 * 64 * 8];   //  9216 B
    __shared__ __align__(16) float wkls[48];
    __shared__ __align__(16) float b2ls[48];
    __shared__ __align__(16) float qils[4][80];          // per-wave qb1, C-layout order

    const int tid  = threadIdx.x;
    const int lane = tid & 63;
    const int wv   = tid >> 6;
    const int l15  = lane & 15;
    const int g    = lane >> 4;
    const int b    = blockIdx.x * 4 + wv;

    const float* kb = keys + (size_t)b * (TT * EE);
    const float* q  = queries + (size_t)b * EE;
    const int len   = keys_length[b];
    const float biass = bias[0];
    const float NEG = -4294967296.0f;

    // --- stage weight frags + wk/b2 into LDS (coalesced) ---
    for (int c = tid; c < 640; c += 256)
        *reinterpret_cast<float4*>(&w1ls[c * 8]) = reinterpret_cast<const float4*>(A1p)[c];
    for (int c = tid; c < 576; c += 256)
        *reinterpret_cast<float4*>(&w2ls[c * 8]) = reinterpret_cast<const float4*>(A2p)[c];
    if (tid < 48) {
        wkls[tid] = (tid < 40) ? wk[tid] : 0.f;
        b2ls[tid] = (tid < 40) ? b2[tid] : 0.f;
    }

    // --- qb1 via MFMA: B = q replicated across all 16 cols -> D[m][n]=qb1pre[m] ---
    {
        bfrag qf0, qf1;
        const float* qp = q + g * 8;
        float4 q0 = *reinterpret_cast<const float4*>(qp);
        float4 q1 = *reinterpret_cast<const float4*>(qp + 4);
        float4 q2 = *reinterpret_cast<const float4*>(qp + 32);
        float4 q3 = *reinterpret_cast<const float4*>(qp + 36);
        PACK(qf0, q0, q1); PACK(qf1, q2, q3);
        #pragma unroll
        for (int mt5 = 0; mt5 < 5; ++mt5) {
            bfrag aq0 = *reinterpret_cast<const bfrag*>(A1q + (((mt5 * 2 + 0) * 64 + lane) << 3));
            bfrag aq1 = *reinterpret_cast<const bfrag*>(A1q + (((mt5 * 2 + 1) * 64 + lane) << 3));
            f32x4 c = { 0.f, 0.f, 0.f, 0.f };
            c = __builtin_amdgcn_mfma_f32_16x16x32_bf16(aq0, qf0, c, 0, 0, 0);
            c = __builtin_amdgcn_mfma_f32_16x16x32_bf16(aq1, qf1, c, 0, 0, 0);
            // add b1 (broadcast float4: <=2 lines/inst) and store this wave's qinit
            float4 bv = *reinterpret_cast<const float4*>(b1 + mt5 * 16 + g * 4);
            if (l15 == 0) {
                float4 o = { c[0] + bv.x, c[1] + bv.y, c[2] + bv.z, c[3] + bv.w };
                *reinterpret_cast<float4*>(&qils[wv][mt5 * 16 + g * 4]) = o;
            }
        }
    }
    __syncthreads();   // the ONLY block barrier: LDS tables ready

    // --- online-softmax state ---
    float acc[16];
    #pragma unroll
    for (int j = 0; j < 16; ++j) acc[j] = 0.f;
    float m = -__builtin_inff(), Z = 0.f;

    // 2-deep key prefetch
    float4 fa0, fa1, fa2, fa3, fb0, fb1, fb2, fb3;
    LOADK(0, fa0, fa1, fa2, fa3);
    LOADK(1, fb0, fb1, fb2, fb3);
    bfrag a0, a1;
    PACK(a0, fa0, fa1); PACK(a1, fa2, fa3);

    for (int mt = 0; mt < 13; mt += 2) {
        BODY(mt, fb0, fb1, fb2, fb3, fa0, fa1, fa2, fa3);
        if (mt + 1 < 13) BODY(mt + 1, fa0, fa1, fa2, fa3, fb0, fb1, fb2, fb3);
    }

    // reduce pooled features over the 16 t-row lanes; lanes l15==0 write out
    #pragma unroll
    for (int j = 0; j < 16; ++j) {
        acc[j] += __shfl_xor(acc[j], 1);
        acc[j] += __shfl_xor(acc[j], 2);
        acc[j] += __shfl_xor(acc[j], 4);
        acc[j] += __shfl_xor(acc[j], 8);
    }
    if (l15 == 0) {
        float inv = __builtin_amdgcn_rcpf(Z);
        float* ob = out + (size_t)b * EE + g * 8;
        float4 o0 = { acc[0] * inv,  acc[1] * inv,  acc[2] * inv,  acc[3] * inv };
        float4 o1 = { acc[4] * inv,  acc[5] * inv,  acc[6] * inv,  acc[7] * inv };
        float4 o2 = { acc[8] * inv,  acc[9] * inv,  acc[10] * inv, acc[11] * inv };
        float4 o3 = { acc[12] * inv, acc[13] * inv, acc[14] * inv, acc[15] * inv };
        *reinterpret_cast<float4*>(ob)      = o0;
        *reinterpret_cast<float4*>(ob + 4)  = o1;
        *reinterpret_cast<float4*>(ob + 32) = o2;
        *reinterpret_cast<float4*>(ob + 36) = o3;
    }
}

extern "C" void kernel_launch(void* const* d_in, const int* in_sizes, int n_in,
                              void* d_out, int out_size, void* d_ws, size_t ws_size,
                              hipStream_t stream) {
    const float* queries = (const float*)d_in[0];
    const float* keys    = (const float*)d_in[1];
    const int*   klen    = (const int*)d_in[2];
    const float* W1      = (const float*)d_in[3];
    const float* b1      = (const float*)d_in[4];
    const float* W2      = (const float*)d_in[5];
    const float* b2      = (const float*)d_in[6];
    const float* wk      = (const float*)d_in[7];
    const float* bias    = (const float*)d_in[8];
    float* out           = (float*)d_out;

    u16* A1p = (u16*)d_ws;                                 // 10240 B
    u16* A2p = (u16*)((char*)d_ws + 10240);                //  9216 B
    u16* A1q = (u16*)((char*)d_ws + 19456);                // 10240 B

    prep_frags<<<20, 256, 0, stream>>>(W1, W2, A1p, A2p, A1q);
    din_mfma<<<1024, 256, 0, stream>>>(queries, keys, klen, b1, b2, wk, bias,
                                       A1p, A2p, A1q, out);
}

// Round 8
// 59.753 us; speedup vs baseline: 3.6664x; 1.0295x over previous
//
#include <hip/hip_runtime.h>
#include <hip/hip_bf16.h>

#define TT 200
#define EE 64
#define NT 7          // 7 tiles x 32 rows = 224 (rows 200..223 masked)

typedef unsigned short u16;
typedef unsigned int u32;
typedef __attribute__((ext_vector_type(8))) short bfrag;   // 8 bf16 in 4 VGPRs
typedef __attribute__((ext_vector_type(4))) float f32x4;

__device__ __forceinline__ u16 f2bf(float f) {
    __hip_bfloat16 h(f);                       // RNE HW cvt
    return __builtin_bit_cast(u16, h);
}
__device__ __forceinline__ float bf2f(u16 h) {
    return __uint_as_float(((u32)h) << 16);
}
__device__ __forceinline__ float sigmoid_fast(float x) {
    return __builtin_amdgcn_rcpf(1.0f + __expf(-x));
}

// Pack W1q^T, W1k^T and W2^T into MFMA *A*-fragment order for swapped GEMMs.
// GEMM1/GEMMq: A slot (g=l>>4, ks, j) <-> k = ks*32 + g*8 + j, m = mt5*16 + l15
// GEMM2: custom bijection matching h1's C-layout residency:
//   i24 = ks*8+j; i24<20: (mt5=i24>>2, r=i24&3), k = mt5*16 + g*4 + r
__global__ void prep_frags(const float* __restrict__ W1, const float* __restrict__ W2,
                           u16* __restrict__ A1p, u16* __restrict__ A2p,
                           u16* __restrict__ A1q) {
    int idx = blockIdx.x * 256 + threadIdx.x;
    if (idx < 5 * 2 * 64 * 8) {   // 5 m-tiles (80) x 2 k-chunks (64)
        int j = idx & 7, l = (idx >> 3) & 63, ks = (idx >> 9) & 1, mt5 = idx >> 10;
        int g = l >> 4, m = mt5 * 16 + (l & 15);
        int k = ks * 32 + g * 8 + j;
        A1p[idx] = f2bf(W1[(64 + k) * 80 + m]);   // key half
        A1q[idx] = f2bf(W1[k * 80 + m]);          // query half
    }
    if (idx < 3 * 3 * 64 * 8) {   // 3 m-tiles (40->48) x 3 k-chunks (80->96)
        int j = idx & 7, l = (idx >> 3) & 63, ks = (idx >> 9) % 3, m2 = idx / 1536;
        int g = l >> 4, m = m2 * 16 + (l & 15);
        int i24 = ks * 8 + j;
        u16 v = 0;
        if (i24 < 20 && m < 40) {
            int mt5 = i24 >> 2, r = i24 & 3;
            int k = mt5 * 16 + g * 4 + r;
            v = f2bf(W2[k * 40 + m]);
        }
        A2p[idx] = v;
    }
}

// load 32 rows (2 groups of 16): group A rows MT*32+l15, group B rows +16
#define LOADK32(MT, QA0, QA1, QA2, QA3, QB0, QB1, QB2, QB3) {           \
    int ra_ = (MT) * 32 + l15;                                          \
    QA0 = QA1 = QA2 = QA3 = make_float4(0.f, 0.f, 0.f, 0.f);            \
    QB0 = QB1 = QB2 = QB3 = make_float4(0.f, 0.f, 0.f, 0.f);            \
    if (ra_ < TT) {                                                     \
        const float* p_ = kb + ra_ * EE + g * 8;                        \
        QA0 = *reinterpret_cast<const float4*>(p_);                     \
        QA1 = *reinterpret_cast<const float4*>(p_ + 4);                 \
        QA2 = *reinterpret_cast<const float4*>(p_ + 32);                \
        QA3 = *reinterpret_cast<const float4*>(p_ + 36);                \
    }                                                                   \
    if (ra_ + 16 < TT) {                                                \
        const float* p_ = kb + (ra_ + 16) * EE + g * 8;                 \
        QB0 = *reinterpret_cast<const float4*>(p_);                     \
        QB1 = *reinterpret_cast<const float4*>(p_ + 4);                 \
        QB2 = *reinterpret_cast<const float4*>(p_ + 32);                \
        QB3 = *reinterpret_cast<const float4*>(p_ + 36);                \
    } }

#define PACK(A, X, Y) {                                                 \
    A[0] = (short)f2bf(X.x); A[1] = (short)f2bf(X.y);                   \
    A[2] = (short)f2bf(X.z); A[3] = (short)f2bf(X.w);                   \
    A[4] = (short)f2bf(Y.x); A[5] = (short)f2bf(Y.y);                   \
    A[6] = (short)f2bf(Y.z); A[7] = (short)f2bf(Y.w); }

// One batch per WAVE; weights block-shared in LDS; 32 rows per iteration.
__global__ __launch_bounds__(256, 2) void din_mfma(
    const float* __restrict__ queries,     // (B,1,64)
    const float* __restrict__ keys,        // (B,200,64)
    const int*   __restrict__ keys_length, // (B,1)
    const float* __restrict__ b1,          // (80)
    const float* __restrict__ b2,          // (40)
    const float* __restrict__ wk,          // (40)
    const float* __restrict__ bias,        // (1)
    const u16*   __restrict__ A1p,
    const u16*   __restrict__ A2p,
    const u16*   __restrict__ A1q,
    float* __restrict__ out)               // (B,1,64)
{
    __shared__ __align__(16) u16 w1ls[5 * 2 * 64 * 8];   // 10240 B
    __shared__ __align__(16) u16 w2ls[3 * 3 * 64 * 8];   //  9216 B
    __shared__ __align__(16) float wkls[48];
    __shared__ __align__(16) float b2ls[48];
    __shared__ __align__(16) float qils[4][80];          // per-wave qb1, C-layout order

    const int tid  = threadIdx.x;
    const int lane = tid & 63;
    const int wv   = tid >> 6;
    const int l15  = lane & 15;
    const int g    = lane >> 4;
    const int b    = blockIdx.x * 4 + wv;

    const float* kb = keys + (size_t)b * (TT * EE);
    const float* q  = queries + (size_t)b * EE;
    const int len   = keys_length[b];
    const float biass = bias[0];
    const float NEG = -4294967296.0f;

    // --- stage weight frags + wk/b2 into LDS (coalesced) ---
    for (int c = tid; c < 640; c += 256)
        *reinterpret_cast<float4*>(&w1ls[c * 8]) = reinterpret_cast<const float4*>(A1p)[c];
    for (int c = tid; c < 576; c += 256)
        *reinterpret_cast<float4*>(&w2ls[c * 8]) = reinterpret_cast<const float4*>(A2p)[c];
    if (tid < 48) {
        wkls[tid] = (tid < 40) ? wk[tid] : 0.f;
        b2ls[tid] = (tid < 40) ? b2[tid] : 0.f;
    }

    // --- qb1 via MFMA: B = q replicated across all 16 cols -> D[m][n]=qb1pre[m] ---
    {
        bfrag qf0, qf1;
        const float* qp = q + g * 8;
        float4 q0 = *reinterpret_cast<const float4*>(qp);
        float4 q1 = *reinterpret_cast<const float4*>(qp + 4);
        float4 q2 = *reinterpret_cast<const float4*>(qp + 32);
        float4 q3 = *reinterpret_cast<const float4*>(qp + 36);
        PACK(qf0, q0, q1); PACK(qf1, q2, q3);
        #pragma unroll
        for (int mt5 = 0; mt5 < 5; ++mt5) {
            bfrag aq0 = *reinterpret_cast<const bfrag*>(A1q + (((mt5 * 2 + 0) * 64 + lane) << 3));
            bfrag aq1 = *reinterpret_cast<const bfrag*>(A1q + (((mt5 * 2 + 1) * 64 + lane) << 3));
            f32x4 c = { 0.f, 0.f, 0.f, 0.f };
            c = __builtin_amdgcn_mfma_f32_16x16x32_bf16(aq0, qf0, c, 0, 0, 0);
            c = __builtin_amdgcn_mfma_f32_16x16x32_bf16(aq1, qf1, c, 0, 0, 0);
            float4 bv = *reinterpret_cast<const float4*>(b1 + mt5 * 16 + g * 4);
            if (l15 == 0) {
                float4 o = { c[0] + bv.x, c[1] + bv.y, c[2] + bv.z, c[3] + bv.w };
                *reinterpret_cast<float4*>(&qils[wv][mt5 * 16 + g * 4]) = o;
            }
        }
    }
    __syncthreads();   // the ONLY block barrier: LDS tables ready

    // --- online-softmax state ---
    float acc[16];
    #pragma unroll
    for (int j = 0; j < 16; ++j) acc[j] = 0.f;
    float m = -__builtin_inff(), Z = 0.f;

    // 1-deep prefetch of 32-row tiles
    float4 qa0, qa1, qa2, qa3, qb0, qb1_, qb2, qb3;
    LOADK32(0, qa0, qa1, qa2, qa3, qb0, qb1_, qb2, qb3);
    bfrag a0, a1, a2, a3;   // a0/a1 = group A feats [g*8..), [32+g*8..); a2/a3 = group B
    PACK(a0, qa0, qa1); PACK(a1, qa2, qa3);
    PACK(a2, qb0, qb1_); PACK(a3, qb2, qb3);

    for (int mt = 0; mt < NT; ++mt) {
        if (mt + 1 < NT) { LOADK32(mt + 1, qa0, qa1, qa2, qa3, qb0, qb1_, qb2, qb3); }

        // GEMM1 swapped, both row groups share each weight read
        f32x4 da[5], db[5];
        #pragma unroll
        for (int mt5 = 0; mt5 < 5; ++mt5) {
            bfrag wA = *reinterpret_cast<const bfrag*>(&w1ls[((mt5 * 2 + 0) * 64 + lane) * 8]);
            bfrag wB = *reinterpret_cast<const bfrag*>(&w1ls[((mt5 * 2 + 1) * 64 + lane) * 8]);
            f32x4 ci = *reinterpret_cast<const f32x4*>(&qils[wv][mt5 * 16 + g * 4]);
            f32x4 ca = ci, cb = ci;
            ca = __builtin_amdgcn_mfma_f32_16x16x32_bf16(wA, a0, ca, 0, 0, 0);
            ca = __builtin_amdgcn_mfma_f32_16x16x32_bf16(wB, a1, ca, 0, 0, 0);
            cb = __builtin_amdgcn_mfma_f32_16x16x32_bf16(wA, a2, cb, 0, 0, 0);
            cb = __builtin_amdgcn_mfma_f32_16x16x32_bf16(wB, a3, cb, 0, 0, 0);
            da[mt5] = ca; db[mt5] = cb;
        }

        // sigmoid -> GEMM2 B-frags in registers (i24 = ks*8+j -> (mt5,r))
        bfrag xa0, xa1, xa2, xb0, xb1, xb2;
        #pragma unroll
        for (int j = 0; j < 8; ++j) {
            xa0[j] = (short)f2bf(sigmoid_fast(da[j >> 2][j & 3]));
            xa1[j] = (short)f2bf(sigmoid_fast(da[(8 + j) >> 2][(8 + j) & 3]));
            xa2[j] = (short)((16 + j) < 20
                        ? f2bf(sigmoid_fast(da[(16 + j) >> 2][(16 + j) & 3])) : 0);
            xb0[j] = (short)f2bf(sigmoid_fast(db[j >> 2][j & 3]));
            xb1[j] = (short)f2bf(sigmoid_fast(db[(8 + j) >> 2][(8 + j) & 3]));
            xb2[j] = (short)((16 + j) < 20
                        ? f2bf(sigmoid_fast(db[(16 + j) >> 2][(16 + j) & 3])) : 0);
        }

        // GEMM2 swapped + wk-dot folded; each u-frag read serves both groups
        float pa = 0.f, pb = 0.f;
        #pragma unroll
        for (int m2 = 0; m2 < 3; ++m2) {
            bfrag u0 = *reinterpret_cast<const bfrag*>(&w2ls[((m2 * 3 + 0) * 64 + lane) * 8]);
            bfrag u1 = *reinterpret_cast<const bfrag*>(&w2ls[((m2 * 3 + 1) * 64 + lane) * 8]);
            bfrag u2 = *reinterpret_cast<const bfrag*>(&w2ls[((m2 * 3 + 2) * 64 + lane) * 8]);
            f32x4 ci = *reinterpret_cast<const f32x4*>(&b2ls[m2 * 16 + g * 4]);
            f32x4 wv4 = *reinterpret_cast<const f32x4*>(&wkls[m2 * 16 + g * 4]);
            f32x4 ca = ci, cb = ci;
            ca = __builtin_amdgcn_mfma_f32_16x16x32_bf16(u0, xa0, ca, 0, 0, 0);
            ca = __builtin_amdgcn_mfma_f32_16x16x32_bf16(u1, xa1, ca, 0, 0, 0);
            ca = __builtin_amdgcn_mfma_f32_16x16x32_bf16(u2, xa2, ca, 0, 0, 0);
            cb = __builtin_amdgcn_mfma_f32_16x16x32_bf16(u0, xb0, cb, 0, 0, 0);
            cb = __builtin_amdgcn_mfma_f32_16x16x32_bf16(u1, xb1, cb, 0, 0, 0);
            cb = __builtin_amdgcn_mfma_f32_16x16x32_bf16(u2, xb2, cb, 0, 0, 0);
            #pragma unroll
            for (int rr = 0; rr < 4; ++rr) {
                pa = fmaf(sigmoid_fast(ca[rr]), wv4[rr], pa);
                pb = fmaf(sigmoid_fast(cb[rr]), wv4[rr], pb);
            }
        }
        pa += __shfl_xor(pa, 16); pa += __shfl_xor(pa, 32);
        pb += __shfl_xor(pb, 16); pb += __shfl_xor(pb, 32);

        const int ra = mt * 32 + l15, rb = ra + 16;
        float sa = (ra < len) ? (pa + biass) : ((ra < TT) ? NEG : -__builtin_inff());
        float sb = (rb < len) ? (pb + biass) : ((rb < TT) ? NEG : -__builtin_inff());

        // one online-softmax update per 32 rows
        float t_ = fmaxf(sa, sb);
        t_ = fmaxf(t_, __shfl_xor(t_, 1));
        t_ = fmaxf(t_, __shfl_xor(t_, 2));
        t_ = fmaxf(t_, __shfl_xor(t_, 4));
        t_ = fmaxf(t_, __shfl_xor(t_, 8));
        if (t_ > m) {
            float sc = __expf(m - t_);
            Z *= sc;
            #pragma unroll
            for (int j = 0; j < 16; ++j) acc[j] *= sc;
            m = t_;
        }
        float ea = __expf(sa - m), eb = __expf(sb - m);
        float zs = ea + eb;
        zs += __shfl_xor(zs, 1);
        zs += __shfl_xor(zs, 2);
        zs += __shfl_xor(zs, 4);
        zs += __shfl_xor(zs, 8);
        Z += zs;

        // fused pooling: both rows' keys still in the bf16 fragments
        #pragma unroll
        for (int j = 0; j < 8; ++j) {
            acc[j]     = fmaf(ea, bf2f((u16)a0[j]), fmaf(eb, bf2f((u16)a2[j]), acc[j]));
            acc[8 + j] = fmaf(ea, bf2f((u16)a1[j]), fmaf(eb, bf2f((u16)a3[j]), acc[8 + j]));
        }

        if (mt + 1 < NT) {
            PACK(a0, qa0, qa1); PACK(a1, qa2, qa3);
            PACK(a2, qb0, qb1_); PACK(a3, qb2, qb3);
        }
    }

    // reduce pooled features over the 16 t-row lanes; lanes l15==0 write out
    #pragma unroll
    for (int j = 0; j < 16; ++j) {
        acc[j] += __shfl_xor(acc[j], 1);
        acc[j] += __shfl_xor(acc[j], 2);
        acc[j] += __shfl_xor(acc[j], 4);
        acc[j] += __shfl_xor(acc[j], 8);
    }
    if (l15 == 0) {
        float inv = __builtin_amdgcn_rcpf(Z);
        float* ob = out + (size_t)b * EE + g * 8;
        float4 o0 = { acc[0] * inv,  acc[1] * inv,  acc[2] * inv,  acc[3] * inv };
        float4 o1 = { acc[4] * inv,  acc[5] * inv,  acc[6] * inv,  acc[7] * inv };
        float4 o2 = { acc[8] * inv,  acc[9] * inv,  acc[10] * inv, acc[11] * inv };
        float4 o3 = { acc[12] * inv, acc[13] * inv, acc[14] * inv, acc[15] * inv };
        *reinterpret_cast<float4*>(ob)      = o0;
        *reinterpret_cast<float4*>(ob + 4)  = o1;
        *reinterpret_cast<float4*>(ob + 32) = o2;
        *reinterpret_cast<float4*>(ob + 36) = o3;
    }
}

extern "C" void kernel_launch(void* const* d_in, const int* in_sizes, int n_in,
                              void* d_out, int out_size, void* d_ws, size_t ws_size,
                              hipStream_t stream) {
    const float* queries = (const float*)d_in[0];
    const float* keys    = (const float*)d_in[1];
    const int*   klen    = (const int*)d_in[2];
    const float* W1      = (const float*)d_in[3];
    const float* b1      = (const float*)d_in[4];
    const float* W2      = (const float*)d_in[5];
    const float* b2      = (const float*)d_in[6];
    const float* wk      = (const float*)d_in[7];
    const float* bias    = (const float*)d_in[8];
    float* out           = (float*)d_out;

    u16* A1p = (u16*)d_ws;                                 // 10240 B
    u16* A2p = (u16*)((char*)d_ws + 10240);                //  9216 B
    u16* A1q = (u16*)((char*)d_ws + 19456);                // 10240 B

    prep_frags<<<20, 256, 0, stream>>>(W1, W2, A1p, A2p, A1q);
    din_mfma<<<1024, 256, 0, stream>>>(queries, keys, klen, b1, b2, wk, bias,
                                       A1p, A2p, A1q, out);
}